// Round 1
// baseline (231.103 us; speedup 1.0000x reference)
//
#include <hip/hip_runtime.h>

#define BB 4
#define SS 2
#define DD 16
#define CH 32          // S*D
#define PP (512*512)   // pixels per item
#define NSEGC 64
#define MARGINF 0.25f
#define BLK 256
#define PIXPT 8                 // pixels per thread
#define CHUNK (BLK*PIXPT)       // 2048 pixels per block
#define NCHUNK (PP/CHUNK)       // 128 blocks per batch

// ---------------- kernel A: segment sums + counts ----------------
__global__ __launch_bounds__(BLK) void k_sums(const float* __restrict__ preds,
                                              const int* __restrict__ labels,
                                              float* __restrict__ g_sums,    // [B][CH][NSEG]
                                              float* __restrict__ g_counts)  // [B][NSEG]
{
    __shared__ float bins[CH * NSEGC];   // [ch][seg]
    __shared__ float cbins[NSEGC];
    const int b    = blockIdx.x / NCHUNK;
    const int base = (blockIdx.x % NCHUNK) * CHUNK;
    const int tid  = threadIdx.x;

    for (int i = tid; i < CH * NSEGC; i += BLK) bins[i] = 0.f;
    if (tid < NSEGC) cbins[tid] = 0.f;

    const int4* lab4 = (const int4*)(labels + (size_t)b * PP + base);
    const int4 l0 = lab4[2 * tid];
    const int4 l1 = lab4[2 * tid + 1];
    const int s0 = l0.x, s1 = l0.y, s2 = l0.z, s3 = l0.w;
    const int s4 = l1.x, s5 = l1.y, s6 = l1.z, s7 = l1.w;
    __syncthreads();

    atomicAdd(&cbins[s0], 1.f); atomicAdd(&cbins[s1], 1.f);
    atomicAdd(&cbins[s2], 1.f); atomicAdd(&cbins[s3], 1.f);
    atomicAdd(&cbins[s4], 1.f); atomicAdd(&cbins[s5], 1.f);
    atomicAdd(&cbins[s6], 1.f); atomicAdd(&cbins[s7], 1.f);

#pragma unroll 4
    for (int ch = 0; ch < CH; ++ch) {
        const float4* src = (const float4*)(preds + ((size_t)b * CH + ch) * PP + base);
        const float4 v0 = src[2 * tid];
        const float4 v1 = src[2 * tid + 1];
        float* bc = &bins[ch * NSEGC];
        atomicAdd(bc + s0, v0.x); atomicAdd(bc + s1, v0.y);
        atomicAdd(bc + s2, v0.z); atomicAdd(bc + s3, v0.w);
        atomicAdd(bc + s4, v1.x); atomicAdd(bc + s5, v1.y);
        atomicAdd(bc + s6, v1.z); atomicAdd(bc + s7, v1.w);
    }
    __syncthreads();

    for (int i = tid; i < CH * NSEGC; i += BLK)
        atomicAdd(&g_sums[(size_t)b * CH * NSEGC + i], bins[i]);
    if (tid < NSEGC)
        atomicAdd(&g_counts[b * NSEGC + tid], cbins[tid]);
}

// ---------------- kernel B: centroids + push loss ----------------
__global__ __launch_bounds__(256) void k_push(const float* __restrict__ g_sums,
                                              const float* __restrict__ g_counts,
                                              float* __restrict__ g_cent,   // [B][NSEG][CH]
                                              float* __restrict__ g_push)   // [B]
{
    __shared__ float centB[CH * NSEGC];  // [ch][seg]
    __shared__ float red[4];
    const int b = blockIdx.x;
    const int tid = threadIdx.x;

    for (int i = tid; i < CH * NSEGC; i += 256) {
        const int ch = i >> 6, seg = i & 63;
        const float cnt = fmaxf(g_counts[b * NSEGC + seg], 1.0f);
        const float c = g_sums[(size_t)b * CH * NSEGC + i] / cnt;
        centB[i] = c;
        g_cent[(size_t)b * NSEGC * CH + seg * CH + ch] = c;
    }
    __syncthreads();

    float acc = 0.f;
    for (int t = tid; t < SS * 2016; t += 256) {
        const int s = t / 2016;
        int rem = t % 2016;
        int i = 0;
        while (rem >= 63 - i) { rem -= 63 - i; ++i; }
        const int j = i + 1 + rem;
        float dsum = 0.f;
#pragma unroll
        for (int d = 0; d < DD; ++d) {
            const int ch = s * DD + d;
            dsum += fabsf(centB[ch * NSEGC + i] - centB[ch * NSEGC + j]);
        }
        const float cd = dsum * (1.f / DD);
        const float r = fmaxf(MARGINF - cd, 0.f);
        acc += r * r;
    }
    for (int o = 32; o > 0; o >>= 1) acc += __shfl_down(acc, o, 64);
    if ((tid & 63) == 0) red[tid >> 6] = acc;
    __syncthreads();
    if (tid == 0)
        g_push[b] = (red[0] + red[1] + red[2] + red[3]) * (1.0f / (SS * 2016));
}

// ---------------- kernel C: pull loss ----------------
__global__ __launch_bounds__(BLK) void k_pull(const float* __restrict__ preds,
                                              const int* __restrict__ labels,
                                              const float* __restrict__ g_cent, // [B][NSEG][CH]
                                              float* __restrict__ g_pull)       // [B]
{
    __shared__ float centL[NSEGC * 33];   // [seg][ch], pad 33 -> spread banks
    __shared__ float red[4];
    const int b    = blockIdx.x / NCHUNK;
    const int base = (blockIdx.x % NCHUNK) * CHUNK;
    const int tid  = threadIdx.x;

    for (int i = tid; i < NSEGC * CH; i += BLK) {
        const int seg = i >> 5, ch = i & 31;
        centL[seg * 33 + ch] = g_cent[(size_t)b * NSEGC * CH + i];
    }
    const int4* lab4 = (const int4*)(labels + (size_t)b * PP + base);
    const int4 l0 = lab4[2 * tid];
    const int4 l1 = lab4[2 * tid + 1];
    const int s0 = l0.x * 33, s1 = l0.y * 33, s2 = l0.z * 33, s3 = l0.w * 33;
    const int s4 = l1.x * 33, s5 = l1.y * 33, s6 = l1.z * 33, s7 = l1.w * 33;
    __syncthreads();

    float total = 0.f;
#pragma unroll
    for (int s = 0; s < SS; ++s) {
        float a0 = 0.f, a1 = 0.f, a2 = 0.f, a3 = 0.f;
        float a4 = 0.f, a5 = 0.f, a6 = 0.f, a7 = 0.f;
#pragma unroll 4
        for (int d = 0; d < DD; ++d) {
            const int ch = s * DD + d;
            const float4* src = (const float4*)(preds + ((size_t)b * CH + ch) * PP + base);
            const float4 v0 = src[2 * tid];
            const float4 v1 = src[2 * tid + 1];
            a0 += fabsf(v0.x - centL[s0 + ch]);
            a1 += fabsf(v0.y - centL[s1 + ch]);
            a2 += fabsf(v0.z - centL[s2 + ch]);
            a3 += fabsf(v0.w - centL[s3 + ch]);
            a4 += fabsf(v1.x - centL[s4 + ch]);
            a5 += fabsf(v1.y - centL[s5 + ch]);
            a6 += fabsf(v1.z - centL[s6 + ch]);
            a7 += fabsf(v1.w - centL[s7 + ch]);
        }
        float q;
        q = a0 * (1.f / DD); total += q * q;
        q = a1 * (1.f / DD); total += q * q;
        q = a2 * (1.f / DD); total += q * q;
        q = a3 * (1.f / DD); total += q * q;
        q = a4 * (1.f / DD); total += q * q;
        q = a5 * (1.f / DD); total += q * q;
        q = a6 * (1.f / DD); total += q * q;
        q = a7 * (1.f / DD); total += q * q;
    }
    for (int o = 32; o > 0; o >>= 1) total += __shfl_down(total, o, 64);
    if ((tid & 63) == 0) red[tid >> 6] = total;
    __syncthreads();
    if (tid == 0)
        atomicAdd(&g_pull[b], red[0] + red[1] + red[2] + red[3]);
}

// ---------------- kernel D: finalize ----------------
__global__ void k_final(const float* __restrict__ g_push,
                        const float* __restrict__ g_pull,
                        float* __restrict__ out)
{
    if (threadIdx.x == 0 && blockIdx.x == 0) {
        float acc = 0.f;
        for (int b = 0; b < BB; ++b)
            acc += g_push[b] + 0.1f * (g_pull[b] * (1.0f / (SS * PP)));
        out[0] = acc * (1.0f / BB);
    }
}

extern "C" void kernel_launch(void* const* d_in, const int* in_sizes, int n_in,
                              void* d_out, int out_size, void* d_ws, size_t ws_size,
                              hipStream_t stream) {
    const float* preds  = (const float*)d_in[0];
    const int*   labels = (const int*)d_in[1];

    float* ws       = (float*)d_ws;
    float* g_sums   = ws;                              // B*CH*NSEG = 8192
    float* g_counts = g_sums + BB * CH * NSEGC;        // B*NSEG    = 256
    float* g_pull   = g_counts + BB * NSEGC;           // B         = 4
    float* g_push   = g_pull + BB;                     // B         = 4
    float* g_cent   = g_push + BB;                     // B*NSEG*CH = 8192

    // zero the accumulated region (sums, counts, pull) every call — replays must not accumulate
    hipMemsetAsync(d_ws, 0, (size_t)(BB * CH * NSEGC + BB * NSEGC + BB) * sizeof(float), stream);

    k_sums <<<BB * NCHUNK, BLK, 0, stream>>>(preds, labels, g_sums, g_counts);
    k_push <<<BB, 256, 0, stream>>>(g_sums, g_counts, g_cent, g_push);
    k_pull <<<BB * NCHUNK, BLK, 0, stream>>>(preds, labels, g_cent, g_pull);
    k_final<<<1, 64, 0, stream>>>(g_push, g_pull, (float*)d_out);
}